// Round 7
// baseline (2060.886 us; speedup 1.0000x reference)
//
#include <hip/hip_runtime.h>

typedef _Float16 f16;
typedef _Float16 f16x8 __attribute__((ext_vector_type(8)));
typedef _Float16 f16x4 __attribute__((ext_vector_type(4)));
typedef float    f32x4 __attribute__((ext_vector_type(4)));
typedef unsigned long long u64;

#define N_   8
#define C_   256
#define H_   128
#define W_   128
#define K_   9
#define PAD_ 4
#define WP_  136            // padded w rows: wp = w + 4, rows 0..135, pads zeroed

#define WELEMS (16*9*8*64*8)        // 589824 = C_*C_*K_ fragment-linear
#define XT_SZ  (N_*WP_*C_)          // 278528 f16 per (buf, hi/lo)
#define NBLK   256
#define NSTEP  253
#define LDS_BYTES (72 * 1024)       // 72 rows x (512B hi | 512B lo); red aliases (32KB)

// swizzled f16 offset within a 256-f16 X row (granule = 8 f16 = 16B; XOR wp&7)
__device__ __host__ inline int xswz(int ci, int wp) {
    return (((ci >> 3) ^ (wp & 7)) << 3) | (ci & 7);
}

// ---------------- weight prep: fragment-linear fp16 hi/lo ----------------
// t = (((ct*9 + k)*8 + cic)*64 + lane)*8 + j ; co = ct*16+(lane&15); ci = cic*32+(lane>>4)*8+j
__global__ __launch_bounds__(256) void prep_w(const float* __restrict__ w,
                                              f16* __restrict__ wh, f16* __restrict__ wl) {
    int t = blockIdx.x * 256 + threadIdx.x;
    if (t >= WELEMS) return;
    int j = t & 7;      int idx = t >> 3;
    int lane = idx & 63; idx >>= 6;
    int cic = idx & 7;   idx >>= 3;
    int k = idx % 9;     int ct = idx / 9;
    int co = ct * 16 + (lane & 15);
    int ci = cic * 32 + (lane >> 4) * 8 + j;
    float wf = w[(co * C_ + ci) * K_ + k];
    f16 hi = (f16)wf;
    f16 lo = (f16)(wf - (float)hi);
    wh[t] = hi;  wl[t] = lo;
}

// ---------------- Xt init: buf0 = fea row0 (swizzled hi/lo), zero pads of both bufs ----------------
__global__ __launch_bounds__(256) void prep_x0(const float* __restrict__ fea,
                                               f16* __restrict__ x0h, f16* __restrict__ x0l,
                                               f16* __restrict__ x1h, f16* __restrict__ x1l) {
    int t = blockIdx.x * 256 + threadIdx.x;
    if (t >= XT_SZ) return;
    int ci = t & 255;
    int wp = (t >> 8) % WP_;
    int n  = t / (WP_ * 256);
    int w  = wp - PAD_;
    bool pad = (unsigned)w >= (unsigned)W_;
    float v = pad ? 0.0f : fea[((size_t)(n * C_ + ci) * H_ + 0) * W_ + w];
    f16 hi = (f16)v;
    f16 lo = (f16)(v - (float)hi);
    size_t dst = ((size_t)n * WP_ + wp) * C_ + xswz(ci, wp);
    x0h[dst] = hi;  x0l[dst] = lo;
    if (pad) { x1h[dst] = (f16)0.f; x1l[dst] = (f16)0.f; }
}

// ---------------- out row0 = fea row0 ----------------
__global__ __launch_bounds__(256) void copy_row0(const float* __restrict__ fea,
                                                 float* __restrict__ out) {
    int idx = blockIdx.x * 256 + threadIdx.x;
    if (idx >= N_ * C_ * W_) return;
    int w = idx % W_;
    int nc = idx / W_;
    size_t off = (size_t)nc * (H_ * W_) + w;
    out[off] = fea[off];
}

// ---------------- persistent scan kernel ----------------
// 256 blocks x 1024 threads (16 waves, 4/SIMD). Block b: n=b&7, ct=(b>>3)&15, whf=b>>7.
// Wave wi: ci-chunk = wi>>1 (32 ci), w-pair = wi&1 (quadrants 2wp, 2wp+1).
// Duty waves: wi<4 -> out stores (q=wi), wi in 4..7 -> X stores (q=wi-4).
// Cross-block X via relaxed AGENT atomics (IF$); per-n flag-array barrier (no RMW).
__global__ __launch_bounds__(1024, 4) void conv_persist(
    f16* __restrict__ x0h, f16* __restrict__ x0l,
    f16* __restrict__ x1h, f16* __restrict__ x1l,
    const f16* __restrict__ whp, const f16* __restrict__ wlp,
    const float* __restrict__ bias, const float* __restrict__ fea,
    float* out, unsigned* ctr)
{
    extern __shared__ unsigned char Xs[];        // 72 KB; red (32 KB) aliases after compute
    float* red = (float*)Xs;

    const int b     = blockIdx.x;
    const int n     = b & 7;
    const int ct    = (b >> 3) & 15;
    const int whf   = b >> 7;
    const int w0    = whf * 64;
    const int tid   = threadIdx.x;
    const int wi    = tid >> 6;
    const int l     = tid & 63;
    const int chunk = wi >> 1;                   // ci chunk 0..7
    const int wpair = wi & 1;                    // quadrant pair
    unsigned* flags = ctr + n * 64;              // 32 flags, one line region per n
    const int bslot = b >> 3;                    // 0..31 within n-group

    // ---- weights -> VGPR, once ----
    f16x8 wk_h[9], wk_l[9];
    #pragma unroll
    for (int k = 0; k < 9; ++k) {
        size_t o = ((((size_t)ct * 9 + k) * 8 + chunk) * 64 + l) * 8;
        wk_h[k] = *(const f16x8*)&whp[o];
        wk_l[k] = *(const f16x8*)&wlp[o];
    }

    f16* bufh[2] = {x0h, x1h};
    f16* bufl[2] = {x0l, x1l};

    const int gcol = (chunk * 4 + (l >> 4)) << 4;  // byte granule base within 512B half-row
    // duty-wave output coords
    const int qd   = wi & 3;
    const int co0  = ct * 16 + (l >> 4) * 4;
    const int wcd  = w0 + qd * 16 + (l & 15);
    float4 bv = *(const float4*)&bias[co0];
    // per-thread staging coords (constant across steps)
    const int srow = tid >> 7;                   // 0..7, + ii*8
    const int shalf = (tid >> 6) & 1;
    const int sg   = tid & 63;

    for (int step = 0; step < NSTEP; ++step) {
        const int  cur   = step & 1;
        const bool fwd   = step < 127;
        const int  h_out = fwd ? (step + 1) : (NSTEP - step);
        const float* radd = fwd ? fea : out;
        const size_t obase = (((size_t)(n * C_ + co0)) * H_ + h_out) * W_ + wcd;

        // ---- stage X (hi|lo) into LDS via coherent (IF$) loads ----
        {
            const u64* gsrc = (const u64*)((shalf ? bufl[cur] : bufh[cur])
                                           + ((size_t)n * WP_ + w0) * C_);
            u64 v[9];
            #pragma unroll
            for (int ii = 0; ii < 9; ++ii)
                v[ii] = __hip_atomic_load(gsrc + (size_t)(srow + ii * 8) * 64 + sg,
                                          __ATOMIC_RELAXED, __HIP_MEMORY_SCOPE_AGENT);
            #pragma unroll
            for (int ii = 0; ii < 9; ++ii)
                *(u64*)(Xs + (srow + ii * 8) * 1024 + shalf * 512 + sg * 8) = v[ii];
        }
        // duty waves prefetch radd (plain cached loads; hide under compute)
        float rv[4] = {0.f, 0.f, 0.f, 0.f};
        if (wi < 8) {
            #pragma unroll
            for (int c = 0; c < 4; ++c)
                rv[c] = radd[obase + (size_t)c * (H_ * W_)];
        }
        __syncthreads();

        // ---- compute: 9k x 2 quadrants x {a0 += Wh*Xh; cr += Wh*Xl + Wl*Xh} ----
        f32x4 a0[2] = {{0,0,0,0},{0,0,0,0}};
        f32x4 cr[2] = {{0,0,0,0},{0,0,0,0}};
        #pragma unroll
        for (int k = 0; k < 9; ++k) {
            #pragma unroll
            for (int qq = 0; qq < 2; ++qq) {
                int r = (wpair * 2 + qq) * 16 + (l & 15) + k;
                const unsigned char* base = Xs + r * 1024 + (gcol ^ ((r & 7) << 4));
                f16x8 bh = *(const f16x8*)base;
                f16x8 bl = *(const f16x8*)(base + 512);
                a0[qq] = __builtin_amdgcn_mfma_f32_16x16x32_f16(wk_h[k], bh, a0[qq], 0, 0, 0);
                cr[qq] = __builtin_amdgcn_mfma_f32_16x16x32_f16(wk_h[k], bl, cr[qq], 0, 0, 0);
                cr[qq] = __builtin_amdgcn_mfma_f32_16x16x32_f16(wk_l[k], bh, cr[qq], 0, 0, 0);
            }
        }
        __syncthreads();          // Xs dead -> reuse as red

        // ---- cross-wave partials: scalar f32 (2-way bank = free) ----
        #pragma unroll
        for (int qq = 0; qq < 2; ++qq) {
            f32x4 sp = a0[qq] + cr[qq];
            int q = wpair * 2 + qq;
            #pragma unroll
            for (int c = 0; c < 4; ++c)
                red[((q * 8 + chunk) * 4 + c) * 64 + l] = sp[c];
        }
        __syncthreads();

        // ---- duty waves: reduce 8 chunks, epilogue ----
        if (wi < 8) {
            float s[4] = {0.f, 0.f, 0.f, 0.f};
            #pragma unroll
            for (int j = 0; j < 8; ++j)
                #pragma unroll
                for (int c = 0; c < 4; ++c)
                    s[c] += red[((qd * 8 + j) * 4 + c) * 64 + l];
            float y[4];
            #pragma unroll
            for (int c = 0; c < 4; ++c)
                y[c] = fmaxf(s[c] + ((const float*)&bv)[c], 0.0f) + rv[c];

            if (wi < 4) {         // out-duty: fp32 result rows
                #pragma unroll
                for (int c = 0; c < 4; ++c)
                    out[obase + (size_t)c * (H_ * W_)] = y[c];
            } else {              // X-duty: swizzled hi/lo carry for next step
                const int wp = wcd + PAD_;
                const size_t xo = ((size_t)n * WP_ + wp) * C_ + xswz(co0, wp);
                f16x4 hv, lv;
                #pragma unroll
                for (int c = 0; c < 4; ++c) {
                    f16 hi = (f16)y[c];
                    hv[c] = hi;
                    lv[c] = (f16)(y[c] - (float)hi);
                }
                u64 uh, ul;
                __builtin_memcpy(&uh, &hv, 8);
                __builtin_memcpy(&ul, &lv, 8);
                __hip_atomic_store((u64*)&bufh[cur ^ 1][xo], uh, __ATOMIC_RELAXED, __HIP_MEMORY_SCOPE_AGENT);
                __hip_atomic_store((u64*)&bufl[cur ^ 1][xo], ul, __ATOMIC_RELAXED, __HIP_MEMORY_SCOPE_AGENT);
            }
        }

        // ---- per-n flag barrier: store own flag, wave0 polls 32 flags in one load ----
        if (step < NSTEP - 1) {
            asm volatile("s_waitcnt vmcnt(0)" ::: "memory");   // each wave drains its X stores
            __syncthreads();                                   // all drained before flag store
            const unsigned tgt = (unsigned)(step + 1);
            if (tid == 0)
                __hip_atomic_store(flags + bslot, tgt, __ATOMIC_RELAXED, __HIP_MEMORY_SCOPE_AGENT);
            if (wi == 0) {
                while (true) {
                    unsigned v = tgt;
                    if (l < 32)
                        v = __hip_atomic_load(flags + l, __ATOMIC_RELAXED, __HIP_MEMORY_SCOPE_AGENT);
                    if (__all((int)(v >= tgt))) break;
                    __builtin_amdgcn_s_sleep(1);
                }
            }
            __syncthreads();
        }
    }
}

// ---------------- fallback (ws too small): fp32 per-step kernels ----------------
__global__ __launch_bounds__(256) void step_f32(
    const float* __restrict__ xprev, const float* __restrict__ radd,
    float* __restrict__ yout, const float* __restrict__ wsrc,
    const float* __restrict__ bias, int h_prev, int h_out)
{
    __shared__ float XsF[C_][40];
    const int t  = threadIdx.x;
    const int bx = blockIdx.x;
    const int n  = bx & 7;
    const int wb = (bx >> 3) & 3;
    const int cb = bx >> 5;
    const int w0 = wb * 32;
    {
        const size_t nbase = (size_t)n * C_ * (H_ * W_) + (size_t)h_prev * W_;
        for (int idx = t; idx < C_ * 40; idx += 256) {
            int ci = idx / 40;
            int j  = idx - ci * 40;
            int w  = w0 - PAD_ + j;
            float v = 0.0f;
            if ((unsigned)w < (unsigned)W_)
                v = xprev[nbase + (size_t)ci * (H_ * W_) + w];
            XsF[ci][j] = v;
        }
    }
    __syncthreads();
    const int co = cb * 32 + (t >> 3);
    const int w4 = (t & 7) * 4;
    const float* wr = wsrc + (size_t)co * (C_ * K_);
    float acc0 = 0.f, acc1 = 0.f, acc2 = 0.f, acc3 = 0.f;
    for (int ci = 0; ci < C_; ci++) {
        float wk[K_];
        #pragma unroll
        for (int k = 0; k < K_; k++) wk[k] = wr[ci * K_ + k];
        float xv[12];
        float4 a = *(const float4*)&XsF[ci][w4];
        float4 bq = *(const float4*)&XsF[ci][w4 + 4];
        float4 c = *(const float4*)&XsF[ci][w4 + 8];
        xv[0]=a.x; xv[1]=a.y; xv[2]=a.z; xv[3]=a.w;
        xv[4]=bq.x; xv[5]=bq.y; xv[6]=bq.z; xv[7]=bq.w;
        xv[8]=c.x; xv[9]=c.y; xv[10]=c.z; xv[11]=c.w;
        #pragma unroll
        for (int k = 0; k < K_; k++) {
            acc0 = fmaf(wk[k], xv[k],     acc0);
            acc1 = fmaf(wk[k], xv[k + 1], acc1);
            acc2 = fmaf(wk[k], xv[k + 2], acc2);
            acc3 = fmaf(wk[k], xv[k + 3], acc3);
        }
    }
    const float bb = bias[co];
    const size_t obase = (((size_t)n * C_ + co) * H_ + h_out) * W_ + w0 + w4;
    float4 r = *(const float4*)&radd[obase];
    float4 o;
    o.x = fmaxf(acc0 + bb, 0.f) + r.x;
    o.y = fmaxf(acc1 + bb, 0.f) + r.y;
    o.z = fmaxf(acc2 + bb, 0.f) + r.z;
    o.w = fmaxf(acc3 + bb, 0.f) + r.w;
    *(float4*)&yout[obase] = o;
}

extern "C" void kernel_launch(void* const* d_in, const int* in_sizes, int n_in,
                              void* d_out, int out_size, void* d_ws, size_t ws_size,
                              hipStream_t stream) {
    const float* fea    = (const float*)d_in[0];
    const float* weight = (const float*)d_in[1];
    const float* bias   = (const float*)d_in[2];
    float* out = (float*)d_out;

    // ws: Wh | Wl | x0h | x0l | x1h | x1l | flags(8 x 256B)
    const size_t need = (size_t)2 * WELEMS * 2 + (size_t)4 * XT_SZ * 2 + 2048;

    copy_row0<<<(N_ * C_ * W_ + 255) / 256, 256, 0, stream>>>(fea, out);

    if (ws_size >= need && d_ws != nullptr) {
        f16* wh  = (f16*)d_ws;
        f16* wl  = wh + WELEMS;
        f16* x0h = wl + WELEMS;
        f16* x0l = x0h + XT_SZ;
        f16* x1h = x0l + XT_SZ;
        f16* x1l = x1h + XT_SZ;
        unsigned* ctr = (unsigned*)(x1l + XT_SZ);

        hipMemsetAsync(ctr, 0, 2048, stream);
        prep_w<<<(WELEMS + 255) / 256, 256, 0, stream>>>(weight, wh, wl);
        prep_x0<<<(XT_SZ + 255) / 256, 256, 0, stream>>>(fea, x0h, x0l, x1h, x1l);

        hipFuncSetAttribute((const void*)conv_persist,
                            hipFuncAttributeMaxDynamicSharedMemorySize, LDS_BYTES);
        conv_persist<<<NBLK, 1024, LDS_BYTES, stream>>>(x0h, x0l, x1h, x1l, wh, wl,
                                                        bias, fea, out, ctr);
    } else {
        for (int h = 1; h < H_; h++)
            step_f32<<<256, 256, 0, stream>>>(out, fea, out, weight, bias, h - 1, h);
        for (int h = H_ - 2; h >= 1; h--)
            step_f32<<<256, 256, 0, stream>>>(out, out, out, weight, bias, h + 1, h);
    }
}

// Round 8
// 1480.953 us; speedup vs baseline: 1.3916x; 1.3916x over previous
//
#include <hip/hip_runtime.h>

typedef _Float16 f16;
typedef _Float16 f16x8 __attribute__((ext_vector_type(8)));
typedef _Float16 f16x4 __attribute__((ext_vector_type(4)));
typedef float    f32x16 __attribute__((ext_vector_type(16)));
typedef unsigned long long u64;

#define N_   8
#define C_   256
#define H_   128
#define W_   128
#define K_   9
#define PAD_ 4
#define WP_  136                    // padded w rows: wp = w + 4, rows 0..135, pads zeroed

#define WELEMS (8*9*16*64*8)        // 589824 = C_*C_*K_ fragment-linear (32x32 layout)
#define XT_SZ  (N_*WP_*256)         // element count for prep_x0 indexing
#define XBUF_F16 (N_*WP_*512)       // one X buffer: per row 256 hi | 256 lo f16 (pre-swizzled)
#define NBLK   256
#define NSTEP  253

// swizzle: granule (8 contiguous ci = 16B) rotated by 2*wp within the 32-granule row
__device__ __host__ inline int xpos(int ci, int wp) {
    int g = ((ci >> 3) + 2 * wp) & 31;
    return g * 8 + (ci & 7);
}

// ---------------- weight prep: fragment-linear fp16 hi/lo for 32x32x16 ----------------
// t = (((ct*9 + k)*16 + c)*64 + lane)*8 + j ; co = ct*32+(lane&31); ci = c*16+(lane>>5)*8+j
__global__ __launch_bounds__(256) void prep_w(const float* __restrict__ w,
                                              f16* __restrict__ wh, f16* __restrict__ wl) {
    int t = blockIdx.x * 256 + threadIdx.x;
    if (t >= WELEMS) return;
    int j = t & 7;      int q = t >> 3;
    int lane = q & 63;  q >>= 6;
    int c = q & 15;     q >>= 4;
    int k = q % 9;      int ct = q / 9;
    int co = ct * 32 + (lane & 31);
    int ci = c * 16 + (lane >> 5) * 8 + j;
    float wf = w[(co * C_ + ci) * K_ + k];
    f16 hi = (f16)wf;
    f16 lo = (f16)(wf - (float)hi);
    wh[t] = hi;  wl[t] = lo;
}

// ---------------- X init: buf0 = fea row0 (swizzled hi|lo per row), zero pads of both bufs ----------------
__global__ __launch_bounds__(256) void prep_x0(const float* __restrict__ fea,
                                               f16* __restrict__ xb0, f16* __restrict__ xb1) {
    int t = blockIdx.x * 256 + threadIdx.x;
    if (t >= XT_SZ) return;
    int ci = t & 255;
    int wp = (t >> 8) % WP_;
    int n  = t / (WP_ * 256);
    int w  = wp - PAD_;
    bool pad = (unsigned)w >= (unsigned)W_;
    float v = pad ? 0.0f : fea[((size_t)(n * C_ + ci) * H_ + 0) * W_ + w];
    f16 hi = (f16)v;
    f16 lo = (f16)(v - (float)hi);
    size_t row = ((size_t)n * WP_ + wp) * 512;
    int p = xpos(ci, wp);
    xb0[row + p] = hi;  xb0[row + 256 + p] = lo;
    if (pad) { xb1[row + p] = (f16)0.f; xb1[row + 256 + p] = (f16)0.f; }
}

// ---------------- out row0 = fea row0 ----------------
__global__ __launch_bounds__(256) void copy_row0(const float* __restrict__ fea,
                                                 float* __restrict__ out) {
    int idx = blockIdx.x * 256 + threadIdx.x;
    if (idx >= N_ * C_ * W_) return;
    int w = idx % W_;
    int nc = idx / W_;
    size_t off = (size_t)nc * (H_ * W_) + w;
    out[off] = fea[off];
}

// ---------------- persistent scan kernel (32x32x16 MFMA) ----------------
// 256 blocks x 512 threads (8 waves, 2/SIMD). Block b: n=b&7, ct=(b>>3)&7 (32 co), wq=b>>6 (32 w).
// Wave wv owns ci-chunk32 wv (2 ci16-chunks). Waves 0-3: epilogue for reg-quad wv.
// Cross-block X via relaxed AGENT atomics (IF$); per-n flag-array barrier (no RMW).
__global__ __launch_bounds__(512, 2) void conv_persist(
    f16* __restrict__ xb0, f16* __restrict__ xb1,
    const f16* __restrict__ whp, const f16* __restrict__ wlp,
    const float* __restrict__ bias, const float* __restrict__ fea,
    float* out, unsigned* ctr)
{
    __shared__ unsigned char Xs[40 * 1024];      // 40 rows x (512B hi | 512B lo); red aliases
    float* red = (float*)Xs;

    const int b   = blockIdx.x;
    const int n   = b & 7;                       // XCD = b%8 -> each n stays on one XCD
    const int ct  = (b >> 3) & 7;
    const int wq  = b >> 6;
    const int w0  = wq * 32;
    const int tid = threadIdx.x;
    const int wv  = tid >> 6;
    const int l   = tid & 63;
    const int m   = l & 31;                      // col (w offset) / A row
    const int hh  = l >> 5;                      // K-half selector
    unsigned* flags = ctr + n * 64;
    const int bslot = b >> 3;                    // 0..31 within n-group

    // ---- weights -> VGPR, once: 18 hi + 18 lo fragments (144 VGPR) ----
    f16x8 wkh[9][2], wkl[9][2];
    #pragma unroll
    for (int k = 0; k < 9; ++k)
        #pragma unroll
        for (int cs = 0; cs < 2; ++cs) {
            size_t o = ((((size_t)ct * 9 + k) * 16 + (wv * 2 + cs)) * 64 + l) * 8;
            wkh[k][cs] = *(const f16x8*)&whp[o];
            wkl[k][cs] = *(const f16x8*)&wlp[o];
        }

    f16* bufs[2] = {xb0, xb1};

    const int dq = wv & 3;                       // reg-quad for epilogue duty (waves 0-3)
    const int co_base = ct * 32 + dq * 8 + hh * 4;
    const size_t HW = (size_t)H_ * W_;
    float4 bv = *(const float4*)&bias[co_base];
    const float bvr[4] = {bv.x, bv.y, bv.z, bv.w};

    for (int step = 0; step < NSTEP; ++step) {
        const int  cur   = step & 1;
        const bool fwd   = step < 127;
        const int  h_out = fwd ? (step + 1) : (NSTEP - step);
        const float* radd = fwd ? fea : out;
        const size_t obase = (((size_t)(n * C_ + co_base)) * H_ + h_out) * W_ + w0 + m;

        // ---- stage X tile (40 rows x 1024B) from IF$, linear copy (pre-swizzled) ----
        {
            const u64* src = (const u64*)(bufs[cur] + ((size_t)n * WP_ + w0) * 512);
            u64 v[10];
            #pragma unroll
            for (int ii = 0; ii < 10; ++ii)
                v[ii] = __hip_atomic_load(src + ii * 512 + tid,
                                          __ATOMIC_RELAXED, __HIP_MEMORY_SCOPE_AGENT);
            #pragma unroll
            for (int ii = 0; ii < 10; ++ii)
                *(u64*)(Xs + (size_t)(ii * 512 + tid) * 8) = v[ii];
        }
        // duty waves prefetch radd (latency hides under compute)
        float rv[4] = {0.f, 0.f, 0.f, 0.f};
        if (wv < 4) {
            #pragma unroll
            for (int c2 = 0; c2 < 4; ++c2)
                rv[c2] = radd[obase + (size_t)c2 * HW];
        }
        __syncthreads();

        // ---- compute: 9k x 2 ci16-chunks x {a0 += Wh*Xh; cr += Wh*Xl + Wl*Xh} ----
        f32x16 a0{}, cr{};
        #pragma unroll
        for (int k = 0; k < 9; ++k) {
            #pragma unroll
            for (int cs = 0; cs < 2; ++cs) {
                const int rl  = m + k;                              // 0..39
                const int gsw = (((wv * 2 + cs) * 2 + hh + 2 * rl) & 31) * 16;
                const unsigned char* base = Xs + rl * 1024 + gsw;
                f16x8 bh = *(const f16x8*)base;
                f16x8 bl = *(const f16x8*)(base + 512);
                a0 = __builtin_amdgcn_mfma_f32_32x32x16_f16(wkh[k][cs], bh, a0, 0, 0, 0);
                cr = __builtin_amdgcn_mfma_f32_32x32x16_f16(wkh[k][cs], bl, cr, 0, 0, 0);
                cr = __builtin_amdgcn_mfma_f32_32x32x16_f16(wkl[k][cs], bh, cr, 0, 0, 0);
            }
        }
        __syncthreads();          // Xs dead -> reuse as red

        // ---- cross-wave partials: scalar f32 (2-way bank = free) ----
        {
            f32x16 sp = a0 + cr;
            #pragma unroll
            for (int reg = 0; reg < 16; ++reg)
                red[(reg * 8 + wv) * 64 + l] = sp[reg];
        }
        __syncthreads();

        // ---- waves 0-3: reduce 8 chunks, epilogue (out + X stores) ----
        if (wv < 4) {
            float y[4];
            #pragma unroll
            for (int c2 = 0; c2 < 4; ++c2) {
                const int reg = dq * 4 + c2;
                float s = 0.f;
                #pragma unroll
                for (int cc = 0; cc < 8; ++cc)
                    s += red[(reg * 8 + cc) * 64 + l];
                y[c2] = fmaxf(s + bvr[c2], 0.0f) + rv[c2];
                out[obase + (size_t)c2 * HW] = y[c2];
            }
            // swizzled hi/lo X carry for next step (co = ci of next step)
            const int wp = w0 + m + PAD_;
            const size_t row = ((size_t)n * WP_ + wp) * 512;
            const int g   = (ct * 4 + dq + 2 * wp) & 31;
            const int pos = g * 8 + hh * 4;
            f16x4 hv, lv;
            #pragma unroll
            for (int c2 = 0; c2 < 4; ++c2) {
                f16 hi = (f16)y[c2];
                hv[c2] = hi;
                lv[c2] = (f16)(y[c2] - (float)hi);
            }
            u64 uh, ul;
            __builtin_memcpy(&uh, &hv, 8);
            __builtin_memcpy(&ul, &lv, 8);
            f16* xbn = bufs[cur ^ 1];
            __hip_atomic_store((u64*)&xbn[row + pos],       uh, __ATOMIC_RELAXED, __HIP_MEMORY_SCOPE_AGENT);
            __hip_atomic_store((u64*)&xbn[row + 256 + pos], ul, __ATOMIC_RELAXED, __HIP_MEMORY_SCOPE_AGENT);
        }

        // ---- per-n flag barrier: store own flag, wave0 polls 32 flags in one load ----
        if (step < NSTEP - 1) {
            asm volatile("s_waitcnt vmcnt(0)" ::: "memory");   // drain X stores
            __syncthreads();                                   // all drained before flag store
            const unsigned tgt = (unsigned)(step + 1);
            if (tid == 0)
                __hip_atomic_store(flags + bslot, tgt, __ATOMIC_RELAXED, __HIP_MEMORY_SCOPE_AGENT);
            if (wv == 0) {
                while (true) {
                    unsigned v = tgt;
                    if (l < 32)
                        v = __hip_atomic_load(flags + l, __ATOMIC_RELAXED, __HIP_MEMORY_SCOPE_AGENT);
                    if (__all((int)(v >= tgt))) break;
                    __builtin_amdgcn_s_sleep(1);
                }
            }
            __syncthreads();
        }
    }
}

// ---------------- fallback (ws too small): fp32 per-step kernels ----------------
__global__ __launch_bounds__(256) void step_f32(
    const float* __restrict__ xprev, const float* __restrict__ radd,
    float* __restrict__ yout, const float* __restrict__ wsrc,
    const float* __restrict__ bias, int h_prev, int h_out)
{
    __shared__ float XsF[C_][40];
    const int t  = threadIdx.x;
    const int bx = blockIdx.x;
    const int n  = bx & 7;
    const int wb = (bx >> 3) & 3;
    const int cb = bx >> 5;
    const int w0 = wb * 32;
    {
        const size_t nbase = (size_t)n * C_ * (H_ * W_) + (size_t)h_prev * W_;
        for (int idx = t; idx < C_ * 40; idx += 256) {
            int ci = idx / 40;
            int j  = idx - ci * 40;
            int w  = w0 - PAD_ + j;
            float v = 0.0f;
            if ((unsigned)w < (unsigned)W_)
                v = xprev[nbase + (size_t)ci * (H_ * W_) + w];
            XsF[ci][j] = v;
        }
    }
    __syncthreads();
    const int co = cb * 32 + (t >> 3);
    const int w4 = (t & 7) * 4;
    const float* wr = wsrc + (size_t)co * (C_ * K_);
    float acc0 = 0.f, acc1 = 0.f, acc2 = 0.f, acc3 = 0.f;
    for (int ci = 0; ci < C_; ci++) {
        float wk[K_];
        #pragma unroll
        for (int k = 0; k < K_; k++) wk[k] = wr[ci * K_ + k];
        float xv[12];
        float4 a = *(const float4*)&XsF[ci][w4];
        float4 bq = *(const float4*)&XsF[ci][w4 + 4];
        float4 c = *(const float4*)&XsF[ci][w4 + 8];
        xv[0]=a.x; xv[1]=a.y; xv[2]=a.z; xv[3]=a.w;
        xv[4]=bq.x; xv[5]=bq.y; xv[6]=bq.z; xv[7]=bq.w;
        xv[8]=c.x; xv[9]=c.y; xv[10]=c.z; xv[11]=c.w;
        #pragma unroll
        for (int k = 0; k < K_; k++) {
            acc0 = fmaf(wk[k], xv[k],     acc0);
            acc1 = fmaf(wk[k], xv[k + 1], acc1);
            acc2 = fmaf(wk[k], xv[k + 2], acc2);
            acc3 = fmaf(wk[k], xv[k + 3], acc3);
        }
    }
    const float bb = bias[co];
    const size_t obase = (((size_t)n * C_ + co) * H_ + h_out) * W_ + w0 + w4;
    float4 r = *(const float4*)&radd[obase];
    float4 o;
    o.x = fmaxf(acc0 + bb, 0.f) + r.x;
    o.y = fmaxf(acc1 + bb, 0.f) + r.y;
    o.z = fmaxf(acc2 + bb, 0.f) + r.z;
    o.w = fmaxf(acc3 + bb, 0.f) + r.w;
    *(float4*)&yout[obase] = o;
}

extern "C" void kernel_launch(void* const* d_in, const int* in_sizes, int n_in,
                              void* d_out, int out_size, void* d_ws, size_t ws_size,
                              hipStream_t stream) {
    const float* fea    = (const float*)d_in[0];
    const float* weight = (const float*)d_in[1];
    const float* bias   = (const float*)d_in[2];
    float* out = (float*)d_out;

    // ws: Wh | Wl | xb0 | xb1 | flags(8 x 256B)
    const size_t need = (size_t)2 * WELEMS * 2 + (size_t)2 * XBUF_F16 * 2 + 2048;

    copy_row0<<<(N_ * C_ * W_ + 255) / 256, 256, 0, stream>>>(fea, out);

    if (ws_size >= need && d_ws != nullptr) {
        f16* wh  = (f16*)d_ws;
        f16* wl  = wh + WELEMS;
        f16* xb0 = wl + WELEMS;
        f16* xb1 = xb0 + XBUF_F16;
        unsigned* ctr = (unsigned*)(xb1 + XBUF_F16);

        hipMemsetAsync(ctr, 0, 2048, stream);
        prep_w<<<(WELEMS + 255) / 256, 256, 0, stream>>>(weight, wh, wl);
        prep_x0<<<(XT_SZ + 255) / 256, 256, 0, stream>>>(fea, xb0, xb1);

        conv_persist<<<NBLK, 512, 0, stream>>>(xb0, xb1, wh, wl, bias, fea, out, ctr);
    } else {
        for (int h = 1; h < H_; h++)
            step_f32<<<256, 256, 0, stream>>>(out, fea, out, weight, bias, h - 1, h);
        for (int h = H_ - 2; h >= 1; h--)
            step_f32<<<256, 256, 0, stream>>>(out, out, out, weight, bias, h + 1, h);
    }
}

// Round 9
// 1390.301 us; speedup vs baseline: 1.4823x; 1.0652x over previous
//
#include <hip/hip_runtime.h>

typedef _Float16 f16;
typedef _Float16 f16x8 __attribute__((ext_vector_type(8)));
typedef _Float16 f16x4 __attribute__((ext_vector_type(4)));
typedef float    f32x16 __attribute__((ext_vector_type(16)));
typedef unsigned long long u64;

#define N_   8
#define C_   256
#define H_   128
#define W_   128
#define K_   9
#define PAD_ 4
#define WP_  136                    // padded w rows: wp = w + 4, rows 0..135, pads zeroed

#define WELEMS (8*9*16*64*8)        // 589824 = C_*C_*K_ fragment-linear (32x32 layout)
#define XT_SZ  (N_*WP_*256)         // element count for prep_x0 indexing
#define XBUF_F16 (N_*WP_*512)       // one X buffer: per row 256 hi | 256 lo f16 (pre-swizzled)
#define NBLK   256
#define NSTEP  253
#define LDS_BYTES (40960 + 32768 + 128)   // X tile | red | wcnt

// swizzle: granule (8 contiguous ci = 16B) rotated by 2*wp within the 32-granule row
__device__ __host__ inline int xpos(int ci, int wp) {
    int g = ((ci >> 3) + 2 * wp) & 31;
    return g * 8 + (ci & 7);
}

// ---------------- weight prep: fragment-linear fp16 hi/lo for 32x32x16 ----------------
// t = (((ct*9 + k)*16 + c)*64 + lane)*8 + j ; co = ct*32+(lane&31); ci = c*16+(lane>>5)*8+j
__global__ __launch_bounds__(256) void prep_w(const float* __restrict__ w,
                                              f16* __restrict__ wh, f16* __restrict__ wl) {
    int t = blockIdx.x * 256 + threadIdx.x;
    if (t >= WELEMS) return;
    int j = t & 7;      int q = t >> 3;
    int lane = q & 63;  q >>= 6;
    int c = q & 15;     q >>= 4;
    int k = q % 9;      int ct = q / 9;
    int co = ct * 32 + (lane & 31);
    int ci = c * 16 + (lane >> 5) * 8 + j;
    float wf = w[(co * C_ + ci) * K_ + k];
    f16 hi = (f16)wf;
    f16 lo = (f16)(wf - (float)hi);
    wh[t] = hi;  wl[t] = lo;
}

// ---------------- X init: buf0 = fea row0 (swizzled hi|lo per row), zero pads of both bufs ----------------
__global__ __launch_bounds__(256) void prep_x0(const float* __restrict__ fea,
                                               f16* __restrict__ xb0, f16* __restrict__ xb1) {
    int t = blockIdx.x * 256 + threadIdx.x;
    if (t >= XT_SZ) return;
    int ci = t & 255;
    int wp = (t >> 8) % WP_;
    int n  = t / (WP_ * 256);
    int w  = wp - PAD_;
    bool pad = (unsigned)w >= (unsigned)W_;
    float v = pad ? 0.0f : fea[((size_t)(n * C_ + ci) * H_ + 0) * W_ + w];
    f16 hi = (f16)v;
    f16 lo = (f16)(v - (float)hi);
    size_t row = ((size_t)n * WP_ + wp) * 512;
    int p = xpos(ci, wp);
    xb0[row + p] = hi;  xb0[row + 256 + p] = lo;
    if (pad) { xb1[row + p] = (f16)0.f; xb1[row + 256 + p] = (f16)0.f; }
}

// ---------------- out row0 = fea row0 ----------------
__global__ __launch_bounds__(256) void copy_row0(const float* __restrict__ fea,
                                                 float* __restrict__ out) {
    int idx = blockIdx.x * 256 + threadIdx.x;
    if (idx >= N_ * C_ * W_) return;
    int w = idx % W_;
    int nc = idx / W_;
    size_t off = (size_t)nc * (H_ * W_) + w;
    out[off] = fea[off];
}

// ---------------- persistent scan kernel (32x32x16 MFMA) ----------------
// 256 blocks x 512 threads (8 waves, pinned 2/SIMD). Block b: n=b&7, ct=(b>>3)&7, wq=b>>6.
// Wave wv owns ci-chunk32 wv. Waves 0-3: reduce+X-store+flag (early), then out-stores.
__global__ __launch_bounds__(512)
__attribute__((amdgpu_waves_per_eu(2, 2)))
void conv_persist(
    f16* __restrict__ xb0, f16* __restrict__ xb1,
    const f16* __restrict__ whp, const f16* __restrict__ wlp,
    const float* __restrict__ bias, const float* __restrict__ fea,
    float* out, unsigned* ctr)
{
    extern __shared__ unsigned char Xs[];            // [0,40960) X tile
    float*    red  = (float*)(Xs + 40960);           // [40960, +32768) partials
    unsigned* wcnt = (unsigned*)(Xs + 40960 + 32768);

    const int b   = blockIdx.x;
    const int n   = b & 7;                           // XCD-local n
    const int ct  = (b >> 3) & 7;
    const int wq  = b >> 6;
    const int w0  = wq * 32;
    const int tid = threadIdx.x;
    const int wv  = tid >> 6;
    const int l   = tid & 63;
    const int m   = l & 31;
    const int hh  = l >> 5;
    unsigned* flags = ctr + n * 64;
    const int bslot = b >> 3;                        // 0..31 within n-group

    if (tid == 0) *wcnt = 0;

    // ---- weights -> VGPR, once: 18 hi + 18 lo fragments (144 VGPR) ----
    f16x8 wkh[9][2], wkl[9][2];
    #pragma unroll
    for (int k = 0; k < 9; ++k)
        #pragma unroll
        for (int cs = 0; cs < 2; ++cs) {
            size_t o = ((((size_t)ct * 9 + k) * 16 + (wv * 2 + cs)) * 64 + l) * 8;
            wkh[k][cs] = *(const f16x8*)&whp[o];
            wkl[k][cs] = *(const f16x8*)&wlp[o];
        }
    // opaque zero add: makes fragments "computed" values so regalloc keeps them
    // resident instead of re-loading from L2 every step (R8: VGPR=116 => reloads).
    {
        f16 z0 = (f16)(0.0f * bias[0]);
        #pragma unroll
        for (int k = 0; k < 9; ++k)
            #pragma unroll
            for (int cs = 0; cs < 2; ++cs) {
                #pragma unroll
                for (int j = 0; j < 8; ++j) { wkh[k][cs][j] += z0; wkl[k][cs][j] += z0; }
            }
    }
    __syncthreads();   // wcnt init visible

    f16* bufs[2] = {xb0, xb1};

    const int dq = wv & 3;
    const int co_base = ct * 32 + dq * 8 + hh * 4;
    const size_t HW = (size_t)H_ * W_;
    float4 bv = *(const float4*)&bias[co_base];
    const float bvr[4] = {bv.x, bv.y, bv.z, bv.w};

    for (int step = 0; step < NSTEP; ++step) {
        const int  cur   = step & 1;
        const bool fwd   = step < 127;
        const int  h_out = fwd ? (step + 1) : (NSTEP - step);
        const float* radd = fwd ? fea : out;
        const size_t obase = (((size_t)(n * C_ + co_base)) * H_ + h_out) * W_ + w0 + m;

        // ---- stage X tile (40 KB) from IF$: 2xu64 loads -> 1x b128 LDS write per granule ----
        {
            const u64* src = (const u64*)(bufs[cur] + ((size_t)n * WP_ + w0) * 512);
            u64 va[5], vb[5];
            #pragma unroll
            for (int ii = 0; ii < 5; ++ii) {
                int g = tid + ii * 512;
                va[ii] = __hip_atomic_load(src + (size_t)g * 2,     __ATOMIC_RELAXED, __HIP_MEMORY_SCOPE_AGENT);
                vb[ii] = __hip_atomic_load(src + (size_t)g * 2 + 1, __ATOMIC_RELAXED, __HIP_MEMORY_SCOPE_AGENT);
            }
            #pragma unroll
            for (int ii = 0; ii < 5; ++ii) {
                int g = tid + ii * 512;
                u64 p[2] = {va[ii], vb[ii]};
                uint4 qd;
                __builtin_memcpy(&qd, p, 16);
                *(uint4*)(Xs + (size_t)g * 16) = qd;
            }
        }
        // duty waves prefetch radd (latency hides under compute)
        float rv[4] = {0.f, 0.f, 0.f, 0.f};
        if (wv < 4) {
            #pragma unroll
            for (int c2 = 0; c2 < 4; ++c2)
                rv[c2] = radd[obase + (size_t)c2 * HW];
        }
        __syncthreads();                             // S1: X tile ready

        // ---- compute: 9k x 2 ci16-chunks x {a0 += Wh*Xh; cr += Wh*Xl + Wl*Xh} ----
        f32x16 a0{}, cr{};
        #pragma unroll
        for (int k = 0; k < 9; ++k) {
            #pragma unroll
            for (int cs = 0; cs < 2; ++cs) {
                const int rl  = m + k;
                const int gsw = (((wv * 2 + cs) * 2 + hh + 2 * rl) & 31) * 16;
                const unsigned char* base = Xs + rl * 1024 + gsw;
                f16x8 bh = *(const f16x8*)base;
                f16x8 bl = *(const f16x8*)(base + 512);
                a0 = __builtin_amdgcn_mfma_f32_32x32x16_f16(wkh[k][cs], bh, a0, 0, 0, 0);
                cr = __builtin_amdgcn_mfma_f32_32x32x16_f16(wkh[k][cs], bl, cr, 0, 0, 0);
                cr = __builtin_amdgcn_mfma_f32_32x32x16_f16(wkl[k][cs], bh, cr, 0, 0, 0);
            }
        }

        // ---- partials to separate red region (overlaps MFMA tail; no pre-sync) ----
        {
            f32x16 sp = a0 + cr;
            #pragma unroll
            for (int reg = 0; reg < 16; ++reg)
                red[(reg * 8 + wv) * 64 + l] = sp[reg];
        }
        __syncthreads();                             // S3: red complete

        if (wv < 4) {
            // reduce 8 chunks for this wave's reg-quad
            float y[4];
            #pragma unroll
            for (int c2 = 0; c2 < 4; ++c2) {
                const int reg = dq * 4 + c2;
                float s = 0.f;
                #pragma unroll
                for (int cc = 0; cc < 8; ++cc)
                    s += red[(reg * 8 + cc) * 64 + l];
                y[c2] = fmaxf(s + bvr[c2], 0.0f) + rv[c2];
            }
            if (step < NSTEP - 1) {
                // X carry store FIRST (critical path), then drain + mini-bar + flag
                const int wp = w0 + m + PAD_;
                const size_t row = ((size_t)n * WP_ + wp) * 512;
                const int g   = (ct * 4 + dq + 2 * wp) & 31;
                const int pos = g * 8 + hh * 4;
                f16x4 hv, lv;
                #pragma unroll
                for (int c2 = 0; c2 < 4; ++c2) {
                    f16 hi = (f16)y[c2];
                    hv[c2] = hi;
                    lv[c2] = (f16)(y[c2] - (float)hi);
                }
                u64 uh, ul;
                __builtin_memcpy(&uh, &hv, 8);
                __builtin_memcpy(&ul, &lv, 8);
                f16* xbn = bufs[cur ^ 1];
                __hip_atomic_store((u64*)&xbn[row + pos],       uh, __ATOMIC_RELAXED, __HIP_MEMORY_SCOPE_AGENT);
                __hip_atomic_store((u64*)&xbn[row + 256 + pos], ul, __ATOMIC_RELAXED, __HIP_MEMORY_SCOPE_AGENT);
                asm volatile("s_waitcnt vmcnt(0)" ::: "memory");   // X stores at IF$
                if (l == 0)
                    __hip_atomic_fetch_add(wcnt, 1u, __ATOMIC_RELAXED, __HIP_MEMORY_SCOPE_WORKGROUP);
                const unsigned tgt = (unsigned)(step + 1);
                if (wv == 0 && l == 0) {
                    while (__hip_atomic_load(wcnt, __ATOMIC_RELAXED, __HIP_MEMORY_SCOPE_WORKGROUP) < 4u * tgt) {}
                    __hip_atomic_store(flags + bslot, tgt, __ATOMIC_RELAXED, __HIP_MEMORY_SCOPE_AGENT);
                }
                // out stores in the poll shadow (same-block consumer only)
                #pragma unroll
                for (int c2 = 0; c2 < 4; ++c2)
                    out[obase + (size_t)c2 * HW] = y[c2];
                if (wv == 0) {
                    while (true) {
                        unsigned v = tgt;
                        if (l < 32)
                            v = __hip_atomic_load(flags + l, __ATOMIC_RELAXED, __HIP_MEMORY_SCOPE_AGENT);
                        if (__all((int)(v >= tgt))) break;
                    }
                }
            } else {
                #pragma unroll
                for (int c2 = 0; c2 < 4; ++c2)
                    out[obase + (size_t)c2 * HW] = y[c2];
            }
        }
        __syncthreads();                             // S4: release (also guards Xs reuse)
    }
}

// ---------------- fallback (ws too small): fp32 per-step kernels ----------------
__global__ __launch_bounds__(256) void step_f32(
    const float* __restrict__ xprev, const float* __restrict__ radd,
    float* __restrict__ yout, const float* __restrict__ wsrc,
    const float* __restrict__ bias, int h_prev, int h_out)
{
    __shared__ float XsF[C_][40];
    const int t  = threadIdx.x;
    const int bx = blockIdx.x;
    const int n  = bx & 7;
    const int wb = (bx >> 3) & 3;
    const int cb = bx >> 5;
    const int w0 = wb * 32;
    {
        const size_t nbase = (size_t)n * C_ * (H_ * W_) + (size_t)h_prev * W_;
        for (int idx = t; idx < C_ * 40; idx += 256) {
            int ci = idx / 40;
            int j  = idx - ci * 40;
            int w  = w0 - PAD_ + j;
            float v = 0.0f;
            if ((unsigned)w < (unsigned)W_)
                v = xprev[nbase + (size_t)ci * (H_ * W_) + w];
            XsF[ci][j] = v;
        }
    }
    __syncthreads();
    const int co = cb * 32 + (t >> 3);
    const int w4 = (t & 7) * 4;
    const float* wr = wsrc + (size_t)co * (C_ * K_);
    float acc0 = 0.f, acc1 = 0.f, acc2 = 0.f, acc3 = 0.f;
    for (int ci = 0; ci < C_; ci++) {
        float wk[K_];
        #pragma unroll
        for (int k = 0; k < K_; k++) wk[k] = wr[ci * K_ + k];
        float xv[12];
        float4 a = *(const float4*)&XsF[ci][w4];
        float4 bq = *(const float4*)&XsF[ci][w4 + 4];
        float4 c = *(const float4*)&XsF[ci][w4 + 8];
        xv[0]=a.x; xv[1]=a.y; xv[2]=a.z; xv[3]=a.w;
        xv[4]=bq.x; xv[5]=bq.y; xv[6]=bq.z; xv[7]=bq.w;
        xv[8]=c.x; xv[9]=c.y; xv[10]=c.z; xv[11]=c.w;
        #pragma unroll
        for (int k = 0; k < K_; k++) {
            acc0 = fmaf(wk[k], xv[k],     acc0);
            acc1 = fmaf(wk[k], xv[k + 1], acc1);
            acc2 = fmaf(wk[k], xv[k + 2], acc2);
            acc3 = fmaf(wk[k], xv[k + 3], acc3);
        }
    }
    const float bb = bias[co];
    const size_t obase = (((size_t)n * C_ + co) * H_ + h_out) * W_ + w0 + w4;
    float4 r = *(const float4*)&radd[obase];
    float4 o;
    o.x = fmaxf(acc0 + bb, 0.f) + r.x;
    o.y = fmaxf(acc1 + bb, 0.f) + r.y;
    o.z = fmaxf(acc2 + bb, 0.f) + r.z;
    o.w = fmaxf(acc3 + bb, 0.f) + r.w;
    *(float4*)&yout[obase] = o;
}

extern "C" void kernel_launch(void* const* d_in, const int* in_sizes, int n_in,
                              void* d_out, int out_size, void* d_ws, size_t ws_size,
                              hipStream_t stream) {
    const float* fea    = (const float*)d_in[0];
    const float* weight = (const float*)d_in[1];
    const float* bias   = (const float*)d_in[2];
    float* out = (float*)d_out;

    // ws: Wh | Wl | xb0 | xb1 | flags(8 x 256B)
    const size_t need = (size_t)2 * WELEMS * 2 + (size_t)2 * XBUF_F16 * 2 + 2048;

    copy_row0<<<(N_ * C_ * W_ + 255) / 256, 256, 0, stream>>>(fea, out);

    if (ws_size >= need && d_ws != nullptr) {
        f16* wh  = (f16*)d_ws;
        f16* wl  = wh + WELEMS;
        f16* xb0 = wl + WELEMS;
        f16* xb1 = xb0 + XBUF_F16;
        unsigned* ctr = (unsigned*)(xb1 + XBUF_F16);

        hipMemsetAsync(ctr, 0, 2048, stream);
        prep_w<<<(WELEMS + 255) / 256, 256, 0, stream>>>(weight, wh, wl);
        prep_x0<<<(XT_SZ + 255) / 256, 256, 0, stream>>>(fea, xb0, xb1);

        hipFuncSetAttribute((const void*)conv_persist,
                            hipFuncAttributeMaxDynamicSharedMemorySize, LDS_BYTES);
        conv_persist<<<NBLK, 512, LDS_BYTES, stream>>>(xb0, xb1, wh, wl, bias, fea, out, ctr);
    } else {
        for (int h = 1; h < H_; h++)
            step_f32<<<256, 256, 0, stream>>>(out, fea, out, weight, bias, h - 1, h);
        for (int h = H_ - 2; h >= 1; h--)
            step_f32<<<256, 256, 0, stream>>>(out, out, out, weight, bias, h + 1, h);
    }
}

// Round 10
// 1368.704 us; speedup vs baseline: 1.5057x; 1.0158x over previous
//
#include <hip/hip_runtime.h>

typedef _Float16 f16;
typedef _Float16 f16x8 __attribute__((ext_vector_type(8)));
typedef _Float16 f16x4 __attribute__((ext_vector_type(4)));
typedef float    f32x16 __attribute__((ext_vector_type(16)));
typedef unsigned long long u64;

#define N_   8
#define C_   256
#define H_   128
#define W_   128
#define K_   9
#define PAD_ 4
#define WP_  136                    // padded w rows: wp = w + 4, rows 0..135, pads zeroed

#define WELEMS (8*9*16*64*8)        // 589824 = C_*C_*K_ fragment-linear (32x32 layout)
#define XT_SZ  (N_*WP_*256)         // element count for prep_x0 indexing
#define XBUF_F16 (N_*WP_*512)       // one X buffer: per row 256 hi | 256 lo f16 (pre-swizzled)
#define NBLK   256
#define NSTEP  253
#define LDS_BYTES (40960 + 32768 + 128)   // X tile | red | wcnt

// swizzle: granule (8 contiguous ci = 16B) rotated by 5*wp within the 32-granule row.
// multiplier 5 (odd): 5*m mod 8 is bijective -> conflict-free b128 reads (R9 used 2 -> 2-way).
__device__ __host__ inline int xpos(int ci, int wp) {
    int g = ((ci >> 3) + 5 * wp) & 31;
    return g * 8 + (ci & 7);
}

// ---------------- weight prep: fragment-linear fp16 hi/lo for 32x32x16 ----------------
// t = (((ct*9 + k)*16 + c)*64 + lane)*8 + j ; co = ct*32+(lane&31); ci = c*16+(lane>>5)*8+j
__global__ __launch_bounds__(256) void prep_w(const float* __restrict__ w,
                                              f16* __restrict__ wh, f16* __restrict__ wl) {
    int t = blockIdx.x * 256 + threadIdx.x;
    if (t >= WELEMS) return;
    int j = t & 7;      int q = t >> 3;
    int lane = q & 63;  q >>= 6;
    int c = q & 15;     q >>= 4;
    int k = q % 9;      int ct = q / 9;
    int co = ct * 32 + (lane & 31);
    int ci = c * 16 + (lane >> 5) * 8 + j;
    float wf = w[(co * C_ + ci) * K_ + k];
    f16 hi = (f16)wf;
    f16 lo = (f16)(wf - (float)hi);
    wh[t] = hi;  wl[t] = lo;
}

// ---------------- X init: buf0 = fea row0 (swizzled hi|lo per row), zero pads of both bufs ----------------
__global__ __launch_bounds__(256) void prep_x0(const float* __restrict__ fea,
                                               f16* __restrict__ xb0, f16* __restrict__ xb1) {
    int t = blockIdx.x * 256 + threadIdx.x;
    if (t >= XT_SZ) return;
    int ci = t & 255;
    int wp = (t >> 8) % WP_;
    int n  = t / (WP_ * 256);
    int w  = wp - PAD_;
    bool pad = (unsigned)w >= (unsigned)W_;
    float v = pad ? 0.0f : fea[((size_t)(n * C_ + ci) * H_ + 0) * W_ + w];
    f16 hi = (f16)v;
    f16 lo = (f16)(v - (float)hi);
    size_t row = ((size_t)n * WP_ + wp) * 512;
    int p = xpos(ci, wp);
    xb0[row + p] = hi;  xb0[row + 256 + p] = lo;
    if (pad) { xb1[row + p] = (f16)0.f; xb1[row + 256 + p] = (f16)0.f; }
}

// ---------------- out row0 = fea row0 ----------------
__global__ __launch_bounds__(256) void copy_row0(const float* __restrict__ fea,
                                                 float* __restrict__ out) {
    int idx = blockIdx.x * 256 + threadIdx.x;
    if (idx >= N_ * C_ * W_) return;
    int w = idx % W_;
    int nc = idx / W_;
    size_t off = (size_t)nc * (H_ * W_) + w;
    out[off] = fea[off];
}

// non-rematerializable definition: forces regalloc to keep the fragment resident
// (R8/R9: plain loads were remat'd-by-reload every step -> 288 KB/CU/step from L2)
#define TIE(x) asm volatile("" : "+v"(x))

// ---------------- persistent scan kernel (32x32x16 MFMA) ----------------
// 256 blocks x 512 threads (8 waves, pinned 2/SIMD). Block b: n=b&7, ct=(b>>3)&7, wq=b>>6.
// Wave wv owns ci-chunk32 wv. Waves 0-3: reduce+X-store+flag (early), then out-stores.
__global__ __launch_bounds__(512)
__attribute__((amdgpu_waves_per_eu(2, 2)))
void conv_persist(
    f16* __restrict__ xb0, f16* __restrict__ xb1,
    const f16* __restrict__ whp, const f16* __restrict__ wlp,
    const float* __restrict__ bias, const float* __restrict__ fea,
    float* out, unsigned* ctr)
{
    extern __shared__ unsigned char Xs[];            // [0,40960) X tile
    float*    red  = (float*)(Xs + 40960);           // [40960, +32768) partials
    unsigned* wcnt = (unsigned*)(Xs + 40960 + 32768);

    const int b   = blockIdx.x;
    const int n   = b & 7;                           // XCD-local n
    const int ct  = (b >> 3) & 7;
    const int wq  = b >> 6;
    const int w0  = wq * 32;
    const int tid = threadIdx.x;
    const int wv  = tid >> 6;
    const int l   = tid & 63;
    const int m   = l & 31;
    const int hh  = l >> 5;
    unsigned* flags = ctr + n * 64;
    const int bslot = b >> 3;                        // 0..31 within n-group

    if (tid == 0) *wcnt = 0;

    // ---- weights -> VGPR, once: 18 hi + 18 lo fragments (144 VGPR) ----
    f16x8 wkh[9][2], wkl[9][2];
    #pragma unroll
    for (int k = 0; k < 9; ++k)
        #pragma unroll
        for (int cs = 0; cs < 2; ++cs) {
            size_t o = ((((size_t)ct * 9 + k) * 16 + (wv * 2 + cs)) * 64 + l) * 8;
            wkh[k][cs] = *(const f16x8*)&whp[o];
            wkl[k][cs] = *(const f16x8*)&wlp[o];
        }
    #pragma unroll
    for (int k = 0; k < 9; ++k)
        #pragma unroll
        for (int cs = 0; cs < 2; ++cs) { TIE(wkh[k][cs]); TIE(wkl[k][cs]); }
    __syncthreads();   // wcnt init visible

    const int dq = wv & 3;
    const int co_base = ct * 32 + dq * 8 + hh * 4;
    const size_t HW = (size_t)H_ * W_;
    float4 bv = *(const float4*)&bias[co_base];
    const float bvr[4] = {bv.x, bv.y, bv.z, bv.w};

    for (int step = 0; step < NSTEP; ++step) {
        const int  cur   = step & 1;
        const bool fwd   = step < 127;
        const int  h_out = fwd ? (step + 1) : (NSTEP - step);
        const float* radd = fwd ? fea : out;
        const size_t obase = (((size_t)(n * C_ + co_base)) * H_ + h_out) * W_ + w0 + m;
        f16* xcur = cur ? xb1 : xb0;
        f16* xnxt = cur ? xb0 : xb1;

        // ---- stage X tile (40 KB) from IF$: 2xu64 loads -> 1x b128 LDS write per granule ----
        {
            const u64* src = (const u64*)(xcur + ((size_t)n * WP_ + w0) * 512);
            u64 va[5], vb[5];
            #pragma unroll
            for (int ii = 0; ii < 5; ++ii) {
                int g = tid + ii * 512;
                va[ii] = __hip_atomic_load(src + (size_t)g * 2,     __ATOMIC_RELAXED, __HIP_MEMORY_SCOPE_AGENT);
                vb[ii] = __hip_atomic_load(src + (size_t)g * 2 + 1, __ATOMIC_RELAXED, __HIP_MEMORY_SCOPE_AGENT);
            }
            #pragma unroll
            for (int ii = 0; ii < 5; ++ii) {
                int g = tid + ii * 512;
                u64 p[2] = {va[ii], vb[ii]};
                uint4 qd;
                __builtin_memcpy(&qd, p, 16);
                *(uint4*)(Xs + (size_t)g * 16) = qd;
            }
        }
        // duty waves prefetch radd (latency hides under compute)
        float rv[4] = {0.f, 0.f, 0.f, 0.f};
        if (wv < 4) {
            #pragma unroll
            for (int c2 = 0; c2 < 4; ++c2)
                rv[c2] = radd[obase + (size_t)c2 * HW];
        }
        __syncthreads();                             // S1: X tile ready

        // ---- compute: 9k x 2 ci16-chunks x {a0 += Wh*Xh; cr += Wh*Xl + Wl*Xh} ----
        f32x16 a0{}, cr{};
        #pragma unroll
        for (int k = 0; k < 9; ++k) {
            #pragma unroll
            for (int cs = 0; cs < 2; ++cs) {
                const int rl  = m + k;
                const int gsw = (((wv * 2 + cs) * 2 + hh + 5 * rl) & 31) * 16;
                const unsigned char* base = Xs + rl * 1024 + gsw;
                f16x8 bh = *(const f16x8*)base;
                f16x8 bl = *(const f16x8*)(base + 512);
                a0 = __builtin_amdgcn_mfma_f32_32x32x16_f16(wkh[k][cs], bh, a0, 0, 0, 0);
                cr = __builtin_amdgcn_mfma_f32_32x32x16_f16(wkh[k][cs], bl, cr, 0, 0, 0);
                cr = __builtin_amdgcn_mfma_f32_32x32x16_f16(wkl[k][cs], bh, cr, 0, 0, 0);
            }
        }

        // ---- partials to separate red region (overlaps MFMA tail; no pre-sync) ----
        {
            f32x16 sp = a0 + cr;
            #pragma unroll
            for (int reg = 0; reg < 16; ++reg)
                red[(reg * 8 + wv) * 64 + l] = sp[reg];
        }
        __syncthreads();                             // S3: red complete

        if (wv < 4) {
            // reduce 8 chunks for this wave's reg-quad
            float y[4];
            #pragma unroll
            for (int c2 = 0; c2 < 4; ++c2) {
                const int reg = dq * 4 + c2;
                float s = 0.f;
                #pragma unroll
                for (int cc = 0; cc < 8; ++cc)
                    s += red[(reg * 8 + cc) * 64 + l];
                y[c2] = fmaxf(s + bvr[c2], 0.0f) + rv[c2];
            }
            if (step < NSTEP - 1) {
                // X carry store FIRST (critical path), then drain + mini-bar + flag
                const int wp = w0 + m + PAD_;
                const size_t row = ((size_t)n * WP_ + wp) * 512;
                const int g   = (ct * 4 + dq + 5 * wp) & 31;
                const int pos = g * 8 + hh * 4;
                f16x4 hv, lv;
                #pragma unroll
                for (int c2 = 0; c2 < 4; ++c2) {
                    f16 hi = (f16)y[c2];
                    hv[c2] = hi;
                    lv[c2] = (f16)(y[c2] - (float)hi);
                }
                u64 uh, ul;
                __builtin_memcpy(&uh, &hv, 8);
                __builtin_memcpy(&ul, &lv, 8);
                __hip_atomic_store((u64*)&xnxt[row + pos],       uh, __ATOMIC_RELAXED, __HIP_MEMORY_SCOPE_AGENT);
                __hip_atomic_store((u64*)&xnxt[row + 256 + pos], ul, __ATOMIC_RELAXED, __HIP_MEMORY_SCOPE_AGENT);
                asm volatile("s_waitcnt vmcnt(0)" ::: "memory");   // X stores at IF$
                if (l == 0)
                    __hip_atomic_fetch_add(wcnt, 1u, __ATOMIC_RELAXED, __HIP_MEMORY_SCOPE_WORKGROUP);
                const unsigned tgt = (unsigned)(step + 1);
                if (wv == 0 && l == 0) {
                    while (__hip_atomic_load(wcnt, __ATOMIC_RELAXED, __HIP_MEMORY_SCOPE_WORKGROUP) < 4u * tgt) {}
                    __hip_atomic_store(flags + bslot, tgt, __ATOMIC_RELAXED, __HIP_MEMORY_SCOPE_AGENT);
                }
                // out stores in the poll shadow (same-block consumer only)
                #pragma unroll
                for (int c2 = 0; c2 < 4; ++c2)
                    out[obase + (size_t)c2 * HW] = y[c2];
                if (wv == 0) {
                    while (true) {
                        unsigned v = tgt;
                        if (l < 32)
                            v = __hip_atomic_load(flags + l, __ATOMIC_RELAXED, __HIP_MEMORY_SCOPE_AGENT);
                        if (__all((int)(v >= tgt))) break;
                    }
                }
            } else {
                #pragma unroll
                for (int c2 = 0; c2 < 4; ++c2)
                    out[obase + (size_t)c2 * HW] = y[c2];
            }
        }
        __syncthreads();                             // S4: release (also guards Xs reuse)
    }
}

// ---------------- fallback (ws too small): fp32 per-step kernels ----------------
__global__ __launch_bounds__(256) void step_f32(
    const float* __restrict__ xprev, const float* __restrict__ radd,
    float* __restrict__ yout, const float* __restrict__ wsrc,
    const float* __restrict__ bias, int h_prev, int h_out)
{
    __shared__ float XsF[C_][40];
    const int t  = threadIdx.x;
    const int bx = blockIdx.x;
    const int n  = bx & 7;
    const int wb = (bx >> 3) & 3;
    const int cb = bx >> 5;
    const int w0 = wb * 32;
    {
        const size_t nbase = (size_t)n * C_ * (H_ * W_) + (size_t)h_prev * W_;
        for (int idx = t; idx < C_ * 40; idx += 256) {
            int ci = idx / 40;
            int j  = idx - ci * 40;
            int w  = w0 - PAD_ + j;
            float v = 0.0f;
            if ((unsigned)w < (unsigned)W_)
                v = xprev[nbase + (size_t)ci * (H_ * W_) + w];
            XsF[ci][j] = v;
        }
    }
    __syncthreads();
    const int co = cb * 32 + (t >> 3);
    const int w4 = (t & 7) * 4;
    const float* wr = wsrc + (size_t)co * (C_ * K_);
    float acc0 = 0.f, acc1 = 0.f, acc2 = 0.f, acc3 = 0.f;
    for (int ci = 0; ci < C_; ci++) {
        float wk[K_];
        #pragma unroll
        for (int k = 0; k < K_; k++) wk[k] = wr[ci * K_ + k];
        float xv[12];
        float4 a = *(const float4*)&XsF[ci][w4];
        float4 bq = *(const float4*)&XsF[ci][w4 + 4];
        float4 c = *(const float4*)&XsF[ci][w4 + 8];
        xv[0]=a.x; xv[1]=a.y; xv[2]=a.z; xv[3]=a.w;
        xv[4]=bq.x; xv[5]=bq.y; xv[6]=bq.z; xv[7]=bq.w;
        xv[8]=c.x; xv[9]=c.y; xv[10]=c.z; xv[11]=c.w;
        #pragma unroll
        for (int k = 0; k < K_; k++) {
            acc0 = fmaf(wk[k], xv[k],     acc0);
            acc1 = fmaf(wk[k], xv[k + 1], acc1);
            acc2 = fmaf(wk[k], xv[k + 2], acc2);
            acc3 = fmaf(wk[k], xv[k + 3], acc3);
        }
    }
    const float bb = bias[co];
    const size_t obase = (((size_t)n * C_ + co) * H_ + h_out) * W_ + w0 + w4;
    float4 r = *(const float4*)&radd[obase];
    float4 o;
    o.x = fmaxf(acc0 + bb, 0.f) + r.x;
    o.y = fmaxf(acc1 + bb, 0.f) + r.y;
    o.z = fmaxf(acc2 + bb, 0.f) + r.z;
    o.w = fmaxf(acc3 + bb, 0.f) + r.w;
    *(float4*)&yout[obase] = o;
}

extern "C" void kernel_launch(void* const* d_in, const int* in_sizes, int n_in,
                              void* d_out, int out_size, void* d_ws, size_t ws_size,
                              hipStream_t stream) {
    const float* fea    = (const float*)d_in[0];
    const float* weight = (const float*)d_in[1];
    const float* bias   = (const float*)d_in[2];
    float* out = (float*)d_out;

    // ws: Wh | Wl | xb0 | xb1 | flags(8 x 256B)
    const size_t need = (size_t)2 * WELEMS * 2 + (size_t)2 * XBUF_F16 * 2 + 2048;

    copy_row0<<<(N_ * C_ * W_ + 255) / 256, 256, 0, stream>>>(fea, out);

    if (ws_size >= need && d_ws != nullptr) {
        f16* wh  = (f16*)d_ws;
        f16* wl  = wh + WELEMS;
        f16* xb0 = wl + WELEMS;
        f16* xb1 = xb0 + XBUF_F16;
        unsigned* ctr = (unsigned*)(xb1 + XBUF_F16);

        hipMemsetAsync(ctr, 0, 2048, stream);
        prep_w<<<(WELEMS + 255) / 256, 256, 0, stream>>>(weight, wh, wl);
        prep_x0<<<(XT_SZ + 255) / 256, 256, 0, stream>>>(fea, xb0, xb1);

        hipFuncSetAttribute((const void*)conv_persist,
                            hipFuncAttributeMaxDynamicSharedMemorySize, LDS_BYTES);
        conv_persist<<<NBLK, 512, LDS_BYTES, stream>>>(xb0, xb1, wh, wl, bias, fea, out, ctr);
    } else {
        for (int h = 1; h < H_; h++)
            step_f32<<<256, 256, 0, stream>>>(out, fea, out, weight, bias, h - 1, h);
        for (int h = H_ - 2; h >= 1; h--)
            step_f32<<<256, 256, 0, stream>>>(out, out, out, weight, bias, h + 1, h);
    }
}

// Round 14
// 1340.928 us; speedup vs baseline: 1.5369x; 1.0207x over previous
//
#include <hip/hip_runtime.h>

typedef _Float16 f16;
typedef _Float16 f16x8 __attribute__((ext_vector_type(8)));
typedef _Float16 f16x4 __attribute__((ext_vector_type(4)));
typedef float    f32x4 __attribute__((ext_vector_type(4)));
typedef float    f32x16 __attribute__((ext_vector_type(16)));
typedef unsigned long long u64;

#define N_   8
#define C_   256
#define H_   128
#define W_   128
#define K_   9
#define PAD_ 4
#define WP_  136                    // padded w rows: wp = w + 4, rows 0..135, pads zeroed

#define WELEMS (8*9*16*64*8)        // 589824 = C_*C_*K_ fragment-linear (32x32 layout)
#define XT_SZ  (N_*WP_*256)
#define XBUF_F16 (N_*WP_*512)       // one X buffer: per row 256 hi | 256 lo f16 (pre-swizzled)
#define NBLK   256
#define NSTEP  253
#define LDS_BYTES (40960 + 32768 + 128)   // X tile | red | wcnt

// granule (8 ci = 16B) rotated by 5*wp within 32-granule row (odd mult -> conflict-free b128)
__device__ __host__ inline int xpos(int ci, int wp) {
    int g = ((ci >> 3) + 5 * wp) & 31;
    return g * 8 + (ci & 7);
}

// ---------------- weight prep ----------------
__global__ __launch_bounds__(256) void prep_w(const float* __restrict__ w,
                                              f16* __restrict__ wh, f16* __restrict__ wl) {
    int t = blockIdx.x * 256 + threadIdx.x;
    if (t >= WELEMS) return;
    int j = t & 7;      int q = t >> 3;
    int lane = q & 63;  q >>= 6;
    int c = q & 15;     q >>= 4;
    int k = q % 9;      int ct = q / 9;
    int co = ct * 32 + (lane & 31);
    int ci = c * 16 + (lane >> 5) * 8 + j;
    float wf = w[(co * C_ + ci) * K_ + k];
    f16 hi = (f16)wf;
    f16 lo = (f16)(wf - (float)hi);
    wh[t] = hi;  wl[t] = lo;
}

// ---------------- X init ----------------
__global__ __launch_bounds__(256) void prep_x0(const float* __restrict__ fea,
                                               f16* __restrict__ xb0, f16* __restrict__ xb1) {
    int t = blockIdx.x * 256 + threadIdx.x;
    if (t >= XT_SZ) return;
    int ci = t & 255;
    int wp = (t >> 8) % WP_;
    int n  = t / (WP_ * 256);
    int w  = wp - PAD_;
    bool pad = (unsigned)w >= (unsigned)W_;
    float v = pad ? 0.0f : fea[((size_t)(n * C_ + ci) * H_ + 0) * W_ + w];
    f16 hi = (f16)v;
    f16 lo = (f16)(v - (float)hi);
    size_t row = ((size_t)n * WP_ + wp) * 512;
    int p = xpos(ci, wp);
    xb0[row + p] = hi;  xb0[row + 256 + p] = lo;
    if (pad) { xb1[row + p] = (f16)0.f; xb1[row + 256 + p] = (f16)0.f; }
}

// ---------------- out row0 = fea row0 ----------------
__global__ __launch_bounds__(256) void copy_row0(const float* __restrict__ fea,
                                                 float* __restrict__ out) {
    int idx = blockIdx.x * 256 + threadIdx.x;
    if (idx >= N_ * C_ * W_) return;
    int w = idx % W_;
    int nc = idx / W_;
    size_t off = (size_t)nc * (H_ * W_) + w;
    out[off] = fea[off];
}

// non-rematerializable definition: forces regalloc to keep fragments resident
#define TIE(x) asm volatile("" : "+v"(x))

// ---------------- persistent scan kernel (32x32x16 MFMA) ----------------
// 256 blocks x 512 threads = exactly 1 block/CU (grid == CU count).
// __launch_bounds__(512, 2): 2 waves/EU min -> 256-VGPR budget, so the 144-VGPR
// weight set can actually stay resident (R8-R10: 128-cap forced per-step reload).
// Block b: n=b&7, ct=(b>>3)&7, wq=b>>6. Wave wv owns ci-chunk32 wv.
// Waves 0-3: reduce + X-store + flag (early), then out-stores in the poll shadow.
__global__ __launch_bounds__(512, 2)
void conv_persist(
    f16* __restrict__ xb0, f16* __restrict__ xb1,
    const f16* __restrict__ whp, const f16* __restrict__ wlp,
    const float* __restrict__ bias, const float* __restrict__ fea,
    float* out, unsigned* ctr)
{
    extern __shared__ unsigned char Xs[];            // [0,40960) X tile
    f32x4*    red  = (f32x4*)(Xs + 40960);           // [40960, +32768) partials (b128 layout)
    unsigned* wcnt = (unsigned*)(Xs + 40960 + 32768);

    const int b   = blockIdx.x;
    const int n   = b & 7;
    const int ct  = (b >> 3) & 7;
    const int wq  = b >> 6;
    const int w0  = wq * 32;
    const int tid = threadIdx.x;
    const int wv  = tid >> 6;
    const int l   = tid & 63;
    const int m   = l & 31;
    const int hh  = l >> 5;
    unsigned* flags = ctr + n * 64;
    const int bslot = b >> 3;                        // 0..31 within n-group

    if (tid == 0) *wcnt = 0;

    // ---- weights -> VGPR, once: 18 hi + 18 lo fragments (144 VGPR) ----
    f16x8 wkh[9][2], wkl[9][2];
    #pragma unroll
    for (int k = 0; k < 9; ++k)
        #pragma unroll
        for (int cs = 0; cs < 2; ++cs) {
            size_t o = ((((size_t)ct * 9 + k) * 16 + (wv * 2 + cs)) * 64 + l) * 8;
            wkh[k][cs] = *(const f16x8*)&whp[o];
            wkl[k][cs] = *(const f16x8*)&wlp[o];
        }
    #pragma unroll
    for (int k = 0; k < 9; ++k)
        #pragma unroll
        for (int cs = 0; cs < 2; ++cs) { TIE(wkh[k][cs]); TIE(wkl[k][cs]); }
    __syncthreads();   // wcnt init visible

    const int dq = wv & 3;
    const int co_base = ct * 32 + dq * 8 + hh * 4;
    const size_t HW = (size_t)H_ * W_;
    float4 bv = *(const float4*)&bias[co_base];
    const float bvr[4] = {bv.x, bv.y, bv.z, bv.w};

    for (int step = 0; step < NSTEP; ++step) {
        const int  cur   = step & 1;
        const bool fwd   = step < 127;
        const int  h_out = fwd ? (step + 1) : (NSTEP - step);
        const float* radd = fwd ? fea : out;
        const size_t obase = (((size_t)(n * C_ + co_base)) * H_ + h_out) * W_ + w0 + m;
        f16* xcur = cur ? xb1 : xb0;
        f16* xnxt = cur ? xb0 : xb1;

        // ---- stage X tile (40 KB) from IF$: 2xu64 loads -> 1x b128 LDS write per granule ----
        {
            const u64* src = (const u64*)(xcur + ((size_t)n * WP_ + w0) * 512);
            u64 va[5], vb2[5];
            #pragma unroll
            for (int ii = 0; ii < 5; ++ii) {
                int g = tid + ii * 512;
                va[ii]  = __hip_atomic_load(src + (size_t)g * 2,     __ATOMIC_RELAXED, __HIP_MEMORY_SCOPE_AGENT);
                vb2[ii] = __hip_atomic_load(src + (size_t)g * 2 + 1, __ATOMIC_RELAXED, __HIP_MEMORY_SCOPE_AGENT);
            }
            #pragma unroll
            for (int ii = 0; ii < 5; ++ii) {
                int g = tid + ii * 512;
                u64 p[2] = {va[ii], vb2[ii]};
                uint4 qd;
                __builtin_memcpy(&qd, p, 16);
                *(uint4*)(Xs + (size_t)g * 16) = qd;
            }
        }
        // duty waves prefetch radd (latency hides under compute)
        float rv[4] = {0.f, 0.f, 0.f, 0.f};
        if (wv < 4) {
            #pragma unroll
            for (int c2 = 0; c2 < 4; ++c2)
                rv[c2] = radd[obase + (size_t)c2 * HW];
        }
        __syncthreads();                             // S1: X tile ready

        // ---- compute: 9k x 2 ci16-chunks x {a0 += Wh*Xh; cr += Wh*Xl + Wl*Xh} ----
        f32x16 a0v{}, crv{};
        #pragma unroll
        for (int k = 0; k < 9; ++k) {
            #pragma unroll
            for (int cs = 0; cs < 2; ++cs) {
                const int rl  = m + k;
                const int gsw = (((wv * 2 + cs) * 2 + hh + 5 * rl) & 31) * 16;
                const unsigned char* base = Xs + rl * 1024 + gsw;
                f16x8 bh = *(const f16x8*)base;
                f16x8 bl = *(const f16x8*)(base + 512);
                a0v = __builtin_amdgcn_mfma_f32_32x32x16_f16(wkh[k][cs], bh, a0v, 0, 0, 0);
                crv = __builtin_amdgcn_mfma_f32_32x32x16_f16(wkh[k][cs], bl, crv, 0, 0, 0);
                crv = __builtin_amdgcn_mfma_f32_32x32x16_f16(wkl[k][cs], bh, crv, 0, 0, 0);
            }
        }

        // ---- partials: b128 writes, [(chunk*4 + regquad)*64 + l] (conflict-free) ----
        {
            f32x16 sp = a0v + crv;
            #pragma unroll
            for (int rq = 0; rq < 4; ++rq) {
                f32x4 qv = {sp[rq * 4 + 0], sp[rq * 4 + 1], sp[rq * 4 + 2], sp[rq * 4 + 3]};
                red[(wv * 4 + rq) * 64 + l] = qv;
            }
        }
        __syncthreads();                             // S3: red complete

        if (wv < 4) {
            // reduce 8 chunks for this wave's reg-quad (8x b128 reads)
            f32x4 s4 = red[(0 * 4 + dq) * 64 + l];
            #pragma unroll
            for (int cc = 1; cc < 8; ++cc)
                s4 += red[(cc * 4 + dq) * 64 + l];
            float y[4];
            #pragma unroll
            for (int c2 = 0; c2 < 4; ++c2)
                y[c2] = fmaxf(s4[c2] + bvr[c2], 0.0f) + rv[c2];

            if (step < NSTEP - 1) {
                // X carry store FIRST (critical path), then drain + mini-bar + flag
                const int wp = w0 + m + PAD_;
                const size_t row = ((size_t)n * WP_ + wp) * 512;
                const int g   = (ct * 4 + dq + 5 * wp) & 31;
                const int pos = g * 8 + hh * 4;
                f16x4 hv, lv;
                #pragma unroll
                for (int c2 = 0; c2 < 4; ++c2) {
                    f16 hi = (f16)y[c2];
                    hv[c2] = hi;
                    lv[c2] = (f16)(y[c2] - (float)hi);
                }
                u64 uh, ul;
                __builtin_memcpy(&uh, &hv, 8);
                __builtin_memcpy(&ul, &lv, 8);
                __hip_atomic_store((u64*)&xnxt[row + pos],       uh, __ATOMIC_RELAXED, __HIP_MEMORY_SCOPE_AGENT);
                __hip_atomic_store((u64*)&xnxt[row + 256 + pos], ul, __ATOMIC_RELAXED, __HIP_MEMORY_SCOPE_AGENT);
                asm volatile("s_waitcnt vmcnt(0)" ::: "memory");   // X stores at IF$
                if (l == 0)
                    __hip_atomic_fetch_add(wcnt, 1u, __ATOMIC_RELAXED, __HIP_MEMORY_SCOPE_WORKGROUP);
                const unsigned tgt = (unsigned)(step + 1);
                if (wv == 0 && l == 0) {
                    while (__hip_atomic_load(wcnt, __ATOMIC_RELAXED, __HIP_MEMORY_SCOPE_WORKGROUP) < 4u * tgt) {}
                    __hip_atomic_store(flags + bslot, tgt, __ATOMIC_RELAXED, __HIP_MEMORY_SCOPE_AGENT);
                }
                // out stores in the poll shadow (same-block consumer only)
                #pragma unroll
                for (int c2 = 0; c2 < 4; ++c2)
                    out[obase + (size_t)c2 * HW] = y[c2];
                if (wv == 0) {
                    while (true) {
                        unsigned v = tgt;
                        if (l < 32)
                            v = __hip_atomic_load(flags + l, __ATOMIC_RELAXED, __HIP_MEMORY_SCOPE_AGENT);
                        if (__all((int)(v >= tgt))) break;
                    }
                }
            } else {
                #pragma unroll
                for (int c2 = 0; c2 < 4; ++c2)
                    out[obase + (size_t)c2 * HW] = y[c2];
            }
        }
        __syncthreads();                             // S4: release (guards Xs reuse)
    }
}

// ---------------- fallback (ws too small): fp32 per-step kernels ----------------
__global__ __launch_bounds__(256) void step_f32(
    const float* __restrict__ xprev, const float* __restrict__ radd,
    float* __restrict__ yout, const float* __restrict__ wsrc,
    const float* __restrict__ bias, int h_prev, int h_out)
{
    __shared__ float XsF[C_][40];
    const int t  = threadIdx.x;
    const int bx = blockIdx.x;
    const int n  = bx & 7;
    const int wb = (bx >> 3) & 3;
    const int cb = bx >> 5;
    const int w0 = wb * 32;
    {
        const size_t nbase = (size_t)n * C_ * (H_ * W_) + (size_t)h_prev * W_;
        for (int idx = t; idx < C_ * 40; idx += 256) {
            int ci = idx / 40;
            int j  = idx - ci * 40;
            int w  = w0 - PAD_ + j;
            float v = 0.0f;
            if ((unsigned)w < (unsigned)W_)
                v = xprev[nbase + (size_t)ci * (H_ * W_) + w];
            XsF[ci][j] = v;
        }
    }
    __syncthreads();
    const int co = cb * 32 + (t >> 3);
    const int w4 = (t & 7) * 4;
    const float* wr = wsrc + (size_t)co * (C_ * K_);
    float acc0 = 0.f, acc1 = 0.f, acc2 = 0.f, acc3 = 0.f;
    for (int ci = 0; ci < C_; ci++) {
        float wk[K_];
        #pragma unroll
        for (int k = 0; k < K_; k++) wk[k] = wr[ci * K_ + k];
        float xv[12];
        float4 a = *(const float4*)&XsF[ci][w4];
        float4 bq = *(const float4*)&XsF[ci][w4 + 4];
        float4 c = *(const float4*)&XsF[ci][w4 + 8];
        xv[0]=a.x; xv[1]=a.y; xv[2]=a.z; xv[3]=a.w;
        xv[4]=bq.x; xv[5]=bq.y; xv[6]=bq.z; xv[7]=bq.w;
        xv[8]=c.x; xv[9]=c.y; xv[10]=c.z; xv[11]=c.w;
        #pragma unroll
        for (int k = 0; k < K_; k++) {
            acc0 = fmaf(wk[k], xv[k],     acc0);
            acc1 = fmaf(wk[k], xv[k + 1], acc1);
            acc2 = fmaf(wk[k], xv[k + 2], acc2);
            acc3 = fmaf(wk[k], xv[k + 3], acc3);
        }
    }
    const float bb = bias[co];
    const size_t obase = (((size_t)n * C_ + co) * H_ + h_out) * W_ + w0 + w4;
    float4 r = *(const float4*)&radd[obase];
    float4 o;
    o.x = fmaxf(acc0 + bb, 0.f) + r.x;
    o.y = fmaxf(acc1 + bb, 0.f) + r.y;
    o.z = fmaxf(acc2 + bb, 0.f) + r.z;
    o.w = fmaxf(acc3 + bb, 0.f) + r.w;
    *(float4*)&yout[obase] = o;
}

extern "C" void kernel_launch(void* const* d_in, const int* in_sizes, int n_in,
                              void* d_out, int out_size, void* d_ws, size_t ws_size,
                              hipStream_t stream) {
    const float* fea    = (const float*)d_in[0];
    const float* weight = (const float*)d_in[1];
    const float* bias   = (const float*)d_in[2];
    float* out = (float*)d_out;

    // ws: Wh | Wl | xb0 | xb1 | flags(8 x 256B)
    const size_t need = (size_t)2 * WELEMS * 2 + (size_t)2 * XBUF_F16 * 2 + 2048;

    copy_row0<<<(N_ * C_ * W_ + 255) / 256, 256, 0, stream>>>(fea, out);

    if (ws_size >= need && d_ws != nullptr) {
        f16* wh  = (f16*)d_ws;
        f16* wl  = wh + WELEMS;
        f16* xb0 = wl + WELEMS;
        f16* xb1 = xb0 + XBUF_F16;
        unsigned* ctr = (unsigned*)(xb1 + XBUF_F16);

        hipMemsetAsync(ctr, 0, 2048, stream);
        prep_w<<<(WELEMS + 255) / 256, 256, 0, stream>>>(weight, wh, wl);
        prep_x0<<<(XT_SZ + 255) / 256, 256, 0, stream>>>(fea, xb0, xb1);

        hipFuncSetAttribute((const void*)conv_persist,
                            hipFuncAttributeMaxDynamicSharedMemorySize, LDS_BYTES);
        conv_persist<<<NBLK, 512, LDS_BYTES, stream>>>(xb0, xb1, wh, wl, bias, fea, out, ctr);
    } else {
        for (int h = 1; h < H_; h++)
            step_f32<<<256, 256, 0, stream>>>(out, fea, out, weight, bias, h - 1, h);
        for (int h = H_ - 2; h >= 1; h--)
            step_f32<<<256, 256, 0, stream>>>(out, out, out, weight, bias, h + 1, h);
    }
}